// Round 1
// baseline (378.975 us; speedup 1.0000x reference)
//
#include <hip/hip_runtime.h>
#include <stdint.h>

// ---------------------------------------------------------------------------
// EfficientDet post-process, multi-dispatch (grid.sync() proved ~100us/sync on
// 8-XCD gfx950 -> kernel-boundary sync instead). This revision cuts 8 nodes
// down to 6 (per-dispatch overhead dominates: aggregate device work is only
// ~100us of the measured 359us):
//   memset(hist0 16KB only) ->
//   k_score   : zero 4.2MB aux region + per-anchor max over 80 cls + 12b hist0
//   k_hist1   : scan(hist0)->d0; 2^20-bin leaf hist + 4096-group summary
//   k_gather  : scans(hist0,summary,leaf group) -> exact 32b threshold T,
//               per-block-aggregated gather
//   k_rankdec : per-thread rank sort of 2048 keys + decode + argmax class
//   k_supres  : 1000x1000 IoU>0.5 bitmatrix + last-block-ticket fused
//               sequential NMS resolve + output write
// ---------------------------------------------------------------------------

#define NK 1000
#define CAP 2048
#define NCLS 80
#define NW 16
typedef unsigned long long ull;

static inline __device__ unsigned fkey(float f) {
  unsigned u = __float_as_uint(f);
  return (u & 0x80000000u) ? ~u : (u | 0x80000000u);
}
static inline __device__ float fkey_inv(unsigned k) {
  unsigned u = (k & 0x80000000u) ? (k & 0x7fffffffu) : ~k;
  return __uint_as_float(u);
}

// Redundant per-block selection scan (blockDim must be 256). Finds largest
// digit with suffix-count >= k and the count strictly above that digit.
__device__ __forceinline__ void scan_select(const unsigned* __restrict__ gh, int nbins,
                                            unsigned k, unsigned* s_sum, unsigned* s_res,
                                            unsigned& digit, unsigned& cum_above) {
  int t = threadIdx.x;
  int chunk = nbins >> 8;
  if (chunk < 1) chunk = 1;
  int base = t * chunk;
  unsigned s = 0;
  for (int b = 0; b < chunk; ++b) s += gh[base + b];
  s_sum[t] = s;
  __syncthreads();
  unsigned ca = 0;
  for (int u = t + 1; u < 256; ++u) ca += s_sum[u];
  if (ca < k && ca + s >= k) {  // exactly one thread
    unsigned cum = ca;
    for (int b = chunk - 1; b >= 0; --b) {
      unsigned c = gh[base + b];
      if (cum + c >= k) { s_res[0] = (unsigned)(base + b); s_res[1] = cum; break; }
      cum += c;
    }
  }
  __syncthreads();
  digit = s_res[0];
  cum_above = s_res[1];
  __syncthreads();
}

// ---- K1: zero aux region + score + key + top-12-bit histogram --------------
__global__ __launch_bounds__(256) void k_score(const float* __restrict__ cla,
                                               unsigned* __restrict__ keys,
                                               unsigned* __restrict__ hist0,
                                               uint4* __restrict__ zreg, int nz4,
                                               int A) {
  __shared__ unsigned lh[4096];
  int t = threadIdx.x;
  // Zero leaf hist (4MB) + summary + meta + cand_keys (consumed only by later
  // dispatches, so no intra-kernel ordering needed). Replaces a memset node.
  {
    const uint4 z = make_uint4(0u, 0u, 0u, 0u);
    int stride = gridDim.x * 256;
    for (int i = blockIdx.x * 256 + t; i < nz4; i += stride) zreg[i] = z;
  }
  for (int i = t; i < 4096; i += 256) lh[i] = 0u;
  __syncthreads();
  const int lane = t & 63, wib = t >> 6;
  const int gwave = blockIdx.x * 4 + wib, nwaves = gridDim.x * 4;
  const int q = lane >> 2, sub = lane & 3;  // 4 lanes per 320B anchor row
  const int ntask = (A + 15) >> 4;
  for (int task = gwave; task < ntask; task += nwaves) {
    int a = task * 16 + q;
    float m = -3.402823466e38f;
    if (a < A) {
      const float4* p = (const float4*)(cla + (size_t)a * NCLS);
#pragma unroll
      for (int j = 0; j < 5; ++j) {
        float4 v = p[sub + j * 4];
        m = fmaxf(m, fmaxf(fmaxf(v.x, v.y), fmaxf(v.z, v.w)));
      }
    }
    m = fmaxf(m, __shfl_xor(m, 1, 64));
    m = fmaxf(m, __shfl_xor(m, 2, 64));
    if (sub == 0 && a < A) {
      unsigned key = fkey(m);
      keys[a] = key;
      atomicAdd(&lh[key >> 20], 1u);
    }
  }
  __syncthreads();
  for (int i = t; i < 4096; i += 256) {
    unsigned c = lh[i];
    if (c) atomicAdd(&hist0[i], c);
  }
}

// ---- K2: 2^20-bin leaf histogram + 4096-group summary ----------------------
__global__ __launch_bounds__(256) void k_hist1(const unsigned* __restrict__ keys,
                                               const unsigned* __restrict__ hist0,
                                               unsigned* __restrict__ leaf,
                                               unsigned* __restrict__ summary, int A) {
  __shared__ unsigned lh[4096];
  __shared__ unsigned s_sum[256];
  __shared__ unsigned s_res[2];
  int t = threadIdx.x;
  unsigned d0, ca;
  scan_select(hist0, 4096, NK, s_sum, s_res, d0, ca);
  for (int i = t; i < 4096; i += 256) lh[i] = 0u;
  __syncthreads();
  int tid = blockIdx.x * 256 + t, nthr = gridDim.x * 256;
  for (int a = tid; a < A; a += nthr) {
    unsigned key = keys[a];
    if ((key >> 20) == d0) {
      unsigned low = key & 0xFFFFFu;
      atomicAdd(&leaf[low], 1u);       // scattered over 1M bins -> low contention
      atomicAdd(&lh[low >> 8], 1u);    // LDS-aggregated group summary
    }
  }
  __syncthreads();
  for (int i = t; i < 4096; i += 256) {
    unsigned c = lh[i];
    if (c) atomicAdd(&summary[i], c);
  }
}

// ---- K3: exact 32-bit threshold + gather (per-block LDS aggregation) -------
__global__ __launch_bounds__(256) void k_gather(const unsigned* __restrict__ keys,
                                                const unsigned* __restrict__ hist0,
                                                const unsigned* __restrict__ leaf,
                                                const unsigned* __restrict__ summary,
                                                unsigned* __restrict__ meta,
                                                ull* __restrict__ cand_keys, int A) {
  __shared__ unsigned s_sum[256];
  __shared__ unsigned s_res[2];
  __shared__ ull lbuf[1024];
  __shared__ unsigned lcnt;
  __shared__ unsigned gbase;
  int t = threadIdx.x;
  unsigned k_rem = NK, d0, g, b, ca;
  scan_select(hist0, 4096, k_rem, s_sum, s_res, d0, ca);
  k_rem -= ca;
  scan_select(summary, 4096, k_rem, s_sum, s_res, g, ca);
  k_rem -= ca;
  scan_select(leaf + (size_t)g * 256, 256, k_rem, s_sum, s_res, b, ca);
  // identical bit layout to the old 3-level threshold: d0(12)|mid(12)|low(8)
  const unsigned T = (d0 << 20) | (g << 8) | b;  // 1000th-largest key
  if (t == 0) lcnt = 0u;
  __syncthreads();
  int tid = blockIdx.x * 256 + t, nthr = gridDim.x * 256;
  for (int a = tid; a < A; a += nthr) {
    unsigned key = keys[a];
    if (key >= T) {
      unsigned pos = atomicAdd(&lcnt, 1u);
      if (pos < 1024)
        lbuf[pos] = ((ull)key << 32) | (ull)(~(unsigned)a);  // (score desc, idx asc)
    }
  }
  __syncthreads();
  if (t == 0) gbase = (lcnt > 0) ? atomicAdd(&meta[0], lcnt) : 0u;
  __syncthreads();
  unsigned n = lcnt < 1024u ? lcnt : 1024u;
  for (unsigned i = t; i < n; i += 256) {
    unsigned pos = gbase + i;
    if (pos < CAP) cand_keys[pos] = lbuf[i];
  }
}

// ---- K4: rank sort + decode + argmax class ---------------------------------
__global__ __launch_bounds__(256) void k_rankdec(
    const float* __restrict__ cla, const float* __restrict__ reg,
    const float* __restrict__ anchors, const int* __restrict__ hp,
    const int* __restrict__ wp, const ull* __restrict__ cand_keys,
    float4* __restrict__ cand_box, float* __restrict__ cand_area,
    float* __restrict__ cand_score, int* __restrict__ cand_cls,
    int* __restrict__ cand_valid) {
  __shared__ ull skeys[CAP];
  int t = threadIdx.x;
  for (int i = t; i < CAP; i += 256) skeys[i] = cand_keys[i];
  __syncthreads();
  int c = blockIdx.x * 256 + t;  // 8 blocks x 256 = CAP
  ull ck = skeys[c];
  if (ck == 0ull) return;  // empty slot
  unsigned cnt = 0;
  const ulonglong2* sk2 = (const ulonglong2*)skeys;
#pragma unroll 4
  for (int j = 0; j < CAP / 2; ++j) {
    ulonglong2 v = sk2[j];
    cnt += (v.x > ck) ? 1u : 0u;
    cnt += (v.y > ck) ? 1u : 0u;
  }
  if (cnt >= NK) return;  // beyond top-1000
  int rank = (int)cnt;
  unsigned a = ~(unsigned)(ck & 0xFFFFFFFFull);
  float score = fkey_inv((unsigned)(ck >> 32));
  float W1 = (float)wp[0] - 1.0f;
  float H1 = (float)hp[0] - 1.0f;
  float4 dd = ((const float4*)reg)[a];
  float4 an = ((const float4*)anchors)[a];
  float wa = an.z - an.x, ha = an.w - an.y;
  float cxa = an.x + 0.5f * wa, cya = an.y + 0.5f * ha;
  float cx = cxa + dd.x * wa, cy = cya + dd.y * ha;
  float w = wa * expf(dd.z), h = ha * expf(dd.w);
  float x1 = fminf(fmaxf(cx - 0.5f * w, 0.0f), W1);
  float y1 = fminf(fmaxf(cy - 0.5f * h, 0.0f), H1);
  float x2 = fminf(fmaxf(cx + 0.5f * w, 0.0f), W1);
  float y2 = fminf(fmaxf(cy + 0.5f * h, 0.0f), H1);
  cand_box[rank] = make_float4(x1, y1, x2, y2);
  cand_area[rank] = fmaxf(x2 - x1, 0.0f) * fmaxf(y2 - y1, 0.0f);
  cand_score[rank] = score;
  cand_valid[rank] = (score > 0.5f) ? 1 : 0;
  // per-thread argmax over 80 classes (first-max tie rule)
  const float* row = cla + (size_t)a * NCLS;
  float m = -3.402823466e38f;
  int ci = 0;
#pragma unroll
  for (int j = 0; j < NCLS; ++j) {
    float v = row[j];
    if (v > m) { m = v; ci = j; }
  }
  cand_cls[rank] = ci;
}

// ---- K5: IoU bitmatrix + last-block-ticket fused NMS resolve + output ------
__global__ __launch_bounds__(256) void k_supres(const float4* __restrict__ cand_box,
                                                const float* __restrict__ cand_area,
                                                const int* __restrict__ cand_valid,
                                                const float* __restrict__ cand_score,
                                                const int* __restrict__ cand_cls,
                                                ull* __restrict__ sup,
                                                unsigned* __restrict__ meta,
                                                float* __restrict__ out) {
  __shared__ float4 bx[NK];
  __shared__ float ar[NK];
  __shared__ ull keep_sh[NW];
  __shared__ int s_last;
  int t = threadIdx.x;
  for (int i = t; i < NK; i += 256) {
    bx[i] = cand_box[i];
    ar[i] = cand_area[i];
  }
  __syncthreads();
  int gidx = blockIdx.x * 256 + t;
  int i = gidx >> 4, w = gidx & 15;
  if (i < NK) {
    float4 bi = bx[i];
    float ai = ar[i];
    ull bits = 0ull;
    int j0 = w * 64;
    int jend = (j0 + 64 < NK) ? (j0 + 64) : NK;
    for (int j = j0; j < jend; ++j) {
      float4 bj = bx[j];
      float xx1 = fmaxf(bi.x, bj.x), yy1 = fmaxf(bi.y, bj.y);
      float xx2 = fminf(bi.z, bj.z), yy2 = fminf(bi.w, bj.w);
      float inter = fmaxf(xx2 - xx1, 0.0f) * fmaxf(yy2 - yy1, 0.0f);
      float uni = ai + ar[j] - inter;
      float iou = inter / fmaxf(uni, 1e-8f);
      if (iou > 0.5f) bits |= (1ull << (j - j0));
    }
    sup[(size_t)i * NW + w] = bits;
  }
  // release our sup rows, then take a ticket (agent scope; per-XCD L2s are
  // not cross-coherent, so device-scope fence + acq_rel atomic are required)
  __threadfence();
  __syncthreads();
  if (t == 0) {
    unsigned done = __hip_atomic_fetch_add(&meta[1], 1u, __ATOMIC_ACQ_REL,
                                           __HIP_MEMORY_SCOPE_AGENT);
    s_last = (done == gridDim.x - 1) ? 1 : 0;
  }
  __syncthreads();
  if (!s_last) return;
  __threadfence();  // acquire: make all other blocks' sup rows visible
  if (t < 64) {
    int lane = t;
    ull keepw[NW];
#pragma unroll
    for (int c = 0; c < NW; ++c) {
      int row = c * 64 + lane;
      ull rw[NW];
      int vld = 0;
      if (row < NK) {
#pragma unroll
        for (int w2 = 0; w2 < NW; ++w2)
          rw[w2] = __hip_atomic_load(&sup[(size_t)row * NW + w2], __ATOMIC_RELAXED,
                                     __HIP_MEMORY_SCOPE_AGENT);
        vld = cand_valid[row];
      } else {
#pragma unroll
        for (int w2 = 0; w2 < NW; ++w2) rw[w2] = 0ull;
      }
      ull prev = 0ull;
#pragma unroll
      for (int w2 = 0; w2 < NW; ++w2)
        if (w2 < c) prev |= rw[w2] & keepw[w2];
      int flags = (vld ? 2 : 0) | ((prev != 0ull) ? 1 : 0);
      unsigned Llo = (unsigned)rw[c];
      unsigned Lhi = (unsigned)(rw[c] >> 32);
      ull kept = 0ull;
      for (int b = 0; b < 64; ++b) {
        int fb = __shfl(flags, b, 64);
        unsigned lo = (unsigned)__shfl((int)Llo, b, 64);
        unsigned hi = (unsigned)__shfl((int)Lhi, b, 64);
        ull Lb = ((ull)hi << 32) | (ull)lo;
        bool kp = ((fb & 2) != 0) && ((fb & 1) == 0) && ((Lb & kept) == 0ull);
        kept |= ((ull)(kp ? 1u : 0u)) << b;
      }
      keepw[c] = kept;
    }
    if (lane == 0) {
#pragma unroll
      for (int w2 = 0; w2 < NW; ++w2) keep_sh[w2] = keepw[w2];
    }
  }
  __syncthreads();
  for (int i2 = t; i2 < NK; i2 += 256) {
    bool kp = (keep_sh[i2 >> 6] >> (i2 & 63)) & 1ull;
    out[i2] = kp ? cand_score[i2] : 0.0f;
    out[NK + i2] = kp ? (float)cand_cls[i2] : -1.0f;  // int output read as float
    float4 bo = cand_box[i2];
    ((float4*)(out + 2 * NK))[i2] = kp ? bo : make_float4(0.f, 0.f, 0.f, 0.f);
  }
}

extern "C" void kernel_launch(void* const* d_in, const int* in_sizes, int n_in,
                              void* d_out, int out_size, void* d_ws, size_t ws_size,
                              hipStream_t stream) {
  const float* cla = (const float*)d_in[0];
  const float* reg = (const float*)d_in[1];
  const float* anchors = (const float*)d_in[2];
  const int* hp = (const int*)d_in[3];
  const int* wp = (const int*)d_in[4];
  float* out = (float*)d_out;
  int A = in_sizes[2] / 4;  // 441936

  char* ws = (char*)d_ws;
  size_t off = 0;
  auto carve = [&](size_t bytes) -> void* {
    void* p = ws + off;
    off += bytes;
    off = (off + 255) & ~(size_t)255;
    return p;
  };
  unsigned* keys = (unsigned*)carve((size_t)A * 4);
  unsigned* hist0 = (unsigned*)carve(4096 * 4);  // zeroed by the memset node
  // contiguous region zeroed inside k_score: leaf|summary|meta|cand_keys
  char* zbase = ws + off;
  unsigned* leaf = (unsigned*)carve((size_t)(1 << 20) * 4);  // 4 MB
  unsigned* summary = (unsigned*)carve(4096 * 4);
  unsigned* meta = (unsigned*)carve(2 * 4);  // [0]=cand_count [1]=ticket
  ull* cand_keys = (ull*)carve(CAP * 8);
  size_t zbytes = (size_t)((ws + off) - zbase);
  int nz4 = (int)(zbytes / 16);
  float4* cand_box = (float4*)carve(1024 * 16);
  float* cand_area = (float*)carve(1024 * 4);
  float* cand_score = (float*)carve(1024 * 4);
  int* cand_cls = (int*)carve(1024 * 4);
  int* cand_valid = (int*)carve(1024 * 4);
  ull* sup = (ull*)carve((size_t)1024 * NW * 8);
  (void)ws_size;
  (void)n_in;
  (void)out_size;

  hipMemsetAsync(hist0, 0, 4096 * 4, stream);
  k_score<<<1024, 256, 0, stream>>>(cla, keys, hist0, (uint4*)zbase, nz4, A);
  k_hist1<<<512, 256, 0, stream>>>(keys, hist0, leaf, summary, A);
  k_gather<<<512, 256, 0, stream>>>(keys, hist0, leaf, summary, meta, cand_keys, A);
  k_rankdec<<<8, 256, 0, stream>>>(cla, reg, anchors, hp, wp, cand_keys, cand_box,
                                   cand_area, cand_score, cand_cls, cand_valid);
  k_supres<<<63, 256, 0, stream>>>(cand_box, cand_area, cand_valid, cand_score,
                                   cand_cls, sup, meta, out);
}

// Round 3
// 329.254 us; speedup vs baseline: 1.1510x; 1.1510x over previous
//
#include <hip/hip_runtime.h>
#include <stdint.h>

// ---------------------------------------------------------------------------
// EfficientDet post-process, multi-dispatch (grid.sync() proved ~100us/sync on
// 8-XCD gfx950 -> kernel-boundary sync instead). 6 nodes:
//   memset(hist0 16KB) ->
//   k_score   : zero 4.2MB aux region + per-anchor max over 80 cls + 12b hist0
//   k_hist1   : scan(hist0)->d0; 2^20-bin leaf hist + 4096-group summary
//   k_gather  : scans(hist0,summary,leaf group) -> exact 32b threshold T,
//               per-block-aggregated gather
//   k_rankdec : per-thread rank sort of 2048 keys + decode + argmax class
//   k_supres  : lower-triangle IoU>0.5 bitmatrix + last-block-ticket fused
//               PARALLEL-FIXPOINT NMS resolve + output write
// Round-1 lesson: serial 1024-step shuffle resolve on one wave was 105us
// (VALUBusy 0.85%). Replaced with monotone fixpoint over LDS kept/not masks.
// Round-2 hardening: sup rows fully defined (zeros above diagonal), phase-2
// word loops fully unrolled (no runtime-indexed array -> no scratch), s_chg
// via benign-race plain store.
// ---------------------------------------------------------------------------

#define NK 1000
#define CAP 2048
#define NCLS 80
#define NW 16
typedef unsigned long long ull;

static inline __device__ unsigned fkey(float f) {
  unsigned u = __float_as_uint(f);
  return (u & 0x80000000u) ? ~u : (u | 0x80000000u);
}
static inline __device__ float fkey_inv(unsigned k) {
  unsigned u = (k & 0x80000000u) ? (k & 0x7fffffffu) : ~k;
  return __uint_as_float(u);
}

// Redundant per-block selection scan (blockDim must be 256). Finds largest
// digit with suffix-count >= k and the count strictly above that digit.
__device__ __forceinline__ void scan_select(const unsigned* __restrict__ gh, int nbins,
                                            unsigned k, unsigned* s_sum, unsigned* s_res,
                                            unsigned& digit, unsigned& cum_above) {
  int t = threadIdx.x;
  int chunk = nbins >> 8;
  if (chunk < 1) chunk = 1;
  int base = t * chunk;
  unsigned s = 0;
  for (int b = 0; b < chunk; ++b) s += gh[base + b];
  s_sum[t] = s;
  __syncthreads();
  unsigned ca = 0;
  for (int u = t + 1; u < 256; ++u) ca += s_sum[u];
  if (ca < k && ca + s >= k) {  // exactly one thread
    unsigned cum = ca;
    for (int b = chunk - 1; b >= 0; --b) {
      unsigned c = gh[base + b];
      if (cum + c >= k) { s_res[0] = (unsigned)(base + b); s_res[1] = cum; break; }
      cum += c;
    }
  }
  __syncthreads();
  digit = s_res[0];
  cum_above = s_res[1];
  __syncthreads();
}

// ---- K1: zero aux region + score + key + top-12-bit histogram --------------
__global__ __launch_bounds__(256) void k_score(const float* __restrict__ cla,
                                               unsigned* __restrict__ keys,
                                               unsigned* __restrict__ hist0,
                                               uint4* __restrict__ zreg, int nz4,
                                               int A) {
  __shared__ unsigned lh[4096];
  int t = threadIdx.x;
  // Zero leaf hist (4MB) + summary + meta + cand_keys (consumed only by later
  // dispatches, so no intra-kernel ordering needed). Replaces a memset node.
  {
    const uint4 z = make_uint4(0u, 0u, 0u, 0u);
    int stride = gridDim.x * 256;
    for (int i = blockIdx.x * 256 + t; i < nz4; i += stride) zreg[i] = z;
  }
  for (int i = t; i < 4096; i += 256) lh[i] = 0u;
  __syncthreads();
  const int lane = t & 63, wib = t >> 6;
  const int gwave = blockIdx.x * 4 + wib, nwaves = gridDim.x * 4;
  const int q = lane >> 2, sub = lane & 3;  // 4 lanes per 320B anchor row
  const int ntask = (A + 15) >> 4;
  for (int task = gwave; task < ntask; task += nwaves) {
    int a = task * 16 + q;
    float m = -3.402823466e38f;
    if (a < A) {
      const float4* p = (const float4*)(cla + (size_t)a * NCLS);
#pragma unroll
      for (int j = 0; j < 5; ++j) {
        float4 v = p[sub + j * 4];
        m = fmaxf(m, fmaxf(fmaxf(v.x, v.y), fmaxf(v.z, v.w)));
      }
    }
    m = fmaxf(m, __shfl_xor(m, 1, 64));
    m = fmaxf(m, __shfl_xor(m, 2, 64));
    if (sub == 0 && a < A) {
      unsigned key = fkey(m);
      keys[a] = key;
      atomicAdd(&lh[key >> 20], 1u);
    }
  }
  __syncthreads();
  for (int i = t; i < 4096; i += 256) {
    unsigned c = lh[i];
    if (c) atomicAdd(&hist0[i], c);
  }
}

// ---- K2: 2^20-bin leaf histogram + 4096-group summary ----------------------
__global__ __launch_bounds__(256) void k_hist1(const unsigned* __restrict__ keys,
                                               const unsigned* __restrict__ hist0,
                                               unsigned* __restrict__ leaf,
                                               unsigned* __restrict__ summary, int A) {
  __shared__ unsigned lh[4096];
  __shared__ unsigned s_sum[256];
  __shared__ unsigned s_res[2];
  int t = threadIdx.x;
  unsigned d0, ca;
  scan_select(hist0, 4096, NK, s_sum, s_res, d0, ca);
  for (int i = t; i < 4096; i += 256) lh[i] = 0u;
  __syncthreads();
  int tid = blockIdx.x * 256 + t, nthr = gridDim.x * 256;
  for (int a = tid; a < A; a += nthr) {
    unsigned key = keys[a];
    if ((key >> 20) == d0) {
      unsigned low = key & 0xFFFFFu;
      atomicAdd(&leaf[low], 1u);       // scattered over 1M bins -> low contention
      atomicAdd(&lh[low >> 8], 1u);    // LDS-aggregated group summary
    }
  }
  __syncthreads();
  for (int i = t; i < 4096; i += 256) {
    unsigned c = lh[i];
    if (c) atomicAdd(&summary[i], c);
  }
}

// ---- K3: exact 32-bit threshold + gather (per-block LDS aggregation) -------
__global__ __launch_bounds__(256) void k_gather(const unsigned* __restrict__ keys,
                                                const unsigned* __restrict__ hist0,
                                                const unsigned* __restrict__ leaf,
                                                const unsigned* __restrict__ summary,
                                                unsigned* __restrict__ meta,
                                                ull* __restrict__ cand_keys, int A) {
  __shared__ unsigned s_sum[256];
  __shared__ unsigned s_res[2];
  __shared__ ull lbuf[1024];
  __shared__ unsigned lcnt;
  __shared__ unsigned gbase;
  int t = threadIdx.x;
  unsigned k_rem = NK, d0, g, b, ca;
  scan_select(hist0, 4096, k_rem, s_sum, s_res, d0, ca);
  k_rem -= ca;
  scan_select(summary, 4096, k_rem, s_sum, s_res, g, ca);
  k_rem -= ca;
  scan_select(leaf + (size_t)g * 256, 256, k_rem, s_sum, s_res, b, ca);
  // identical bit layout to the old 3-level threshold: d0(12)|mid(12)|low(8)
  const unsigned T = (d0 << 20) | (g << 8) | b;  // 1000th-largest key
  if (t == 0) lcnt = 0u;
  __syncthreads();
  int tid = blockIdx.x * 256 + t, nthr = gridDim.x * 256;
  for (int a = tid; a < A; a += nthr) {
    unsigned key = keys[a];
    if (key >= T) {
      unsigned pos = atomicAdd(&lcnt, 1u);
      if (pos < 1024)
        lbuf[pos] = ((ull)key << 32) | (ull)(~(unsigned)a);  // (score desc, idx asc)
    }
  }
  __syncthreads();
  if (t == 0) gbase = (lcnt > 0) ? atomicAdd(&meta[0], lcnt) : 0u;
  __syncthreads();
  unsigned n = lcnt < 1024u ? lcnt : 1024u;
  for (unsigned i = t; i < n; i += 256) {
    unsigned pos = gbase + i;
    if (pos < CAP) cand_keys[pos] = lbuf[i];
  }
}

// ---- K4: rank sort + decode + argmax class ---------------------------------
__global__ __launch_bounds__(256) void k_rankdec(
    const float* __restrict__ cla, const float* __restrict__ reg,
    const float* __restrict__ anchors, const int* __restrict__ hp,
    const int* __restrict__ wp, const ull* __restrict__ cand_keys,
    float4* __restrict__ cand_box, float* __restrict__ cand_area,
    float* __restrict__ cand_score, int* __restrict__ cand_cls,
    int* __restrict__ cand_valid) {
  __shared__ ull skeys[CAP];
  int t = threadIdx.x;
  for (int i = t; i < CAP; i += 256) skeys[i] = cand_keys[i];
  __syncthreads();
  int c = blockIdx.x * 256 + t;  // 8 blocks x 256 = CAP
  ull ck = skeys[c];
  if (ck == 0ull) return;  // empty slot
  unsigned cnt = 0;
  const ulonglong2* sk2 = (const ulonglong2*)skeys;
#pragma unroll 4
  for (int j = 0; j < CAP / 2; ++j) {
    ulonglong2 v = sk2[j];
    cnt += (v.x > ck) ? 1u : 0u;
    cnt += (v.y > ck) ? 1u : 0u;
  }
  if (cnt >= NK) return;  // beyond top-1000
  int rank = (int)cnt;
  unsigned a = ~(unsigned)(ck & 0xFFFFFFFFull);
  float score = fkey_inv((unsigned)(ck >> 32));
  float W1 = (float)wp[0] - 1.0f;
  float H1 = (float)hp[0] - 1.0f;
  float4 dd = ((const float4*)reg)[a];
  float4 an = ((const float4*)anchors)[a];
  float wa = an.z - an.x, ha = an.w - an.y;
  float cxa = an.x + 0.5f * wa, cya = an.y + 0.5f * ha;
  float cx = cxa + dd.x * wa, cy = cya + dd.y * ha;
  float w = wa * expf(dd.z), h = ha * expf(dd.w);
  float x1 = fminf(fmaxf(cx - 0.5f * w, 0.0f), W1);
  float y1 = fminf(fmaxf(cy - 0.5f * h, 0.0f), H1);
  float x2 = fminf(fmaxf(cx + 0.5f * w, 0.0f), W1);
  float y2 = fminf(fmaxf(cy + 0.5f * h, 0.0f), H1);
  cand_box[rank] = make_float4(x1, y1, x2, y2);
  cand_area[rank] = fmaxf(x2 - x1, 0.0f) * fmaxf(y2 - y1, 0.0f);
  cand_score[rank] = score;
  cand_valid[rank] = (score > 0.5f) ? 1 : 0;
  // per-thread argmax over 80 classes (first-max tie rule)
  const float* row = cla + (size_t)a * NCLS;
  float m = -3.402823466e38f;
  int ci = 0;
#pragma unroll
  for (int j = 0; j < NCLS; ++j) {
    float v = row[j];
    if (v > m) { m = v; ci = j; }
  }
  cand_cls[rank] = ci;
}

// ---- K5: lower-tri IoU bitmatrix + ticket + parallel-fixpoint resolve ------
__global__ __launch_bounds__(1024) void k_supres(const float4* __restrict__ cand_box,
                                                 const float* __restrict__ cand_area,
                                                 const int* __restrict__ cand_valid,
                                                 const float* __restrict__ cand_score,
                                                 const int* __restrict__ cand_cls,
                                                 ull* __restrict__ sup,
                                                 unsigned* __restrict__ meta,
                                                 float* __restrict__ out) {
  __shared__ float4 bx[NK];
  __shared__ float ar[NK];
  __shared__ unsigned keptm[32], notm[32];  // 1024-bit kept / decided-not masks
  __shared__ int s_chg;
  __shared__ int s_last;
  int t = threadIdx.x;
  for (int i = t; i < NK; i += 1024) {
    bx[i] = cand_box[i];
    ar[i] = cand_area[i];
  }
  __syncthreads();
  // ---- phase 1: IoU bitmatrix. Every (i,w) word is written (zeros above the
  // diagonal) so phase 2 never reads an undefined word. j staggered by w:
  // distinct bank groups across the 16 w-lanes -> 2-way conflict (free).
  {
    int gidx = blockIdx.x * 1024 + t;
    int i = gidx >> 4, w = gidx & 15;
    int j0 = w * 64;
    if (i < NK) {
      ull bits = 0ull;
      if (j0 <= i) {
        float4 bi = bx[i];
        float ai = ar[i];
#pragma unroll 4
        for (int s = 0; s < 64; ++s) {
          int jj = (s + w) & 63;
          int j = j0 + jj;
          if (j < NK) {
            float4 bj = bx[j];
            float xx1 = fmaxf(bi.x, bj.x), yy1 = fmaxf(bi.y, bj.y);
            float xx2 = fminf(bi.z, bj.z), yy2 = fminf(bi.w, bj.w);
            float inter = fmaxf(xx2 - xx1, 0.0f) * fmaxf(yy2 - yy1, 0.0f);
            float uni = ai + ar[j] - inter;
            float iou = inter / fmaxf(uni, 1e-8f);
            if (iou > 0.5f) bits |= (1ull << jj);
          }
        }
      }
      sup[(size_t)i * NW + w] = bits;
    }
  }
  // ---- release our sup rows, take a ticket (agent scope: per-XCD L2s are
  // not cross-coherent; consumer reads sup via agent-scope atomic loads).
  __threadfence();
  __syncthreads();
  if (t == 0) {
    unsigned done = __hip_atomic_fetch_add(&meta[1], 1u, __ATOMIC_ACQ_REL,
                                           __HIP_MEMORY_SCOPE_AGENT);
    s_last = (done == gridDim.x - 1) ? 1 : 0;
    s_chg = 0;
  }
  __syncthreads();
  if (!s_last) return;
  // ---- phase 2 (last block only): monotone-fixpoint greedy NMS.
  // Row i kept    <=> valid[i] and every strict-lower suppressor decided-not.
  // Row i dropped <=> !valid[i] or some kept suppressor.
  // Bits in keptm/notm are set only when final-true -> mid-round races and
  // torn 64-bit reassembly are benign (monotone). Each round the smallest
  // undecided row necessarily decides -> <= chain-length rounds.
  if (t < 32) { keptm[t] = 0u; notm[t] = 0u; }
  int i = t;
  bool active = (i < NK);
  int wi = i >> 6;
  ull rw[NW];  // fully unrolled static indexing only -> registers, not scratch
  bool decided = true;
  if (active) {
#pragma unroll
    for (int w = 0; w < NW; ++w)
      rw[w] = __hip_atomic_load(&sup[(size_t)i * NW + w], __ATOMIC_RELAXED,
                                __HIP_MEMORY_SCOPE_AGENT);
    int bi = i & 63;
    ull dmask = (bi == 0) ? 0ull : ((1ull << bi) - 1ull);
#pragma unroll
    for (int w = 0; w < NW; ++w)
      rw[w] = (w < wi) ? rw[w] : ((w == wi) ? (rw[w] & dmask) : 0ull);
    decided = (cand_valid[i] == 0);
  }
  __syncthreads();
  if (active && decided) atomicOr(&notm[i >> 5], 1u << (i & 31));  // invalid -> drop
  __syncthreads();
  for (int round = 0; round < NK; ++round) {
    if (active && !decided) {
      ull hit = 0ull, pot = 0ull;
#pragma unroll
      for (int w = 0; w < NW; ++w) {
        ull km = ((ull)keptm[2 * w + 1] << 32) | (ull)keptm[2 * w];
        ull nm = ((ull)notm[2 * w + 1] << 32) | (ull)notm[2 * w];
        hit |= rw[w] & km;
        pot |= rw[w] & ~(km | nm);
      }
      if (hit) {
        decided = true;
        atomicOr(&notm[i >> 5], 1u << (i & 31));
        s_chg = 1;  // benign race: all writers store 1
      } else if (!pot) {
        decided = true;
        atomicOr(&keptm[i >> 5], 1u << (i & 31));
        s_chg = 1;
      }
    }
    __syncthreads();
    if (s_chg == 0) break;
    __syncthreads();
    if (t == 0) s_chg = 0;
    __syncthreads();
  }
  // ---- output write
  for (int i2 = t; i2 < NK; i2 += 1024) {
    bool kp = (keptm[i2 >> 5] >> (i2 & 31)) & 1u;
    out[i2] = kp ? cand_score[i2] : 0.0f;
    out[NK + i2] = kp ? (float)cand_cls[i2] : -1.0f;  // int output read as float
    float4 bo = bx[i2];
    ((float4*)(out + 2 * NK))[i2] = kp ? bo : make_float4(0.f, 0.f, 0.f, 0.f);
  }
}

extern "C" void kernel_launch(void* const* d_in, const int* in_sizes, int n_in,
                              void* d_out, int out_size, void* d_ws, size_t ws_size,
                              hipStream_t stream) {
  const float* cla = (const float*)d_in[0];
  const float* reg = (const float*)d_in[1];
  const float* anchors = (const float*)d_in[2];
  const int* hp = (const int*)d_in[3];
  const int* wp = (const int*)d_in[4];
  float* out = (float*)d_out;
  int A = in_sizes[2] / 4;  // 441936

  char* ws = (char*)d_ws;
  size_t off = 0;
  auto carve = [&](size_t bytes) -> void* {
    void* p = ws + off;
    off += bytes;
    off = (off + 255) & ~(size_t)255;
    return p;
  };
  unsigned* keys = (unsigned*)carve((size_t)A * 4);
  unsigned* hist0 = (unsigned*)carve(4096 * 4);  // zeroed by the memset node
  // contiguous region zeroed inside k_score: leaf|summary|meta|cand_keys
  char* zbase = ws + off;
  unsigned* leaf = (unsigned*)carve((size_t)(1 << 20) * 4);  // 4 MB
  unsigned* summary = (unsigned*)carve(4096 * 4);
  unsigned* meta = (unsigned*)carve(2 * 4);  // [0]=cand_count [1]=ticket
  ull* cand_keys = (ull*)carve(CAP * 8);
  size_t zbytes = (size_t)((ws + off) - zbase);
  int nz4 = (int)(zbytes / 16);
  float4* cand_box = (float4*)carve(1024 * 16);
  float* cand_area = (float*)carve(1024 * 4);
  float* cand_score = (float*)carve(1024 * 4);
  int* cand_cls = (int*)carve(1024 * 4);
  int* cand_valid = (int*)carve(1024 * 4);
  ull* sup = (ull*)carve((size_t)1024 * NW * 8);
  (void)ws_size;
  (void)n_in;
  (void)out_size;

  hipMemsetAsync(hist0, 0, 4096 * 4, stream);
  k_score<<<1024, 256, 0, stream>>>(cla, keys, hist0, (uint4*)zbase, nz4, A);
  k_hist1<<<512, 256, 0, stream>>>(keys, hist0, leaf, summary, A);
  k_gather<<<512, 256, 0, stream>>>(keys, hist0, leaf, summary, meta, cand_keys, A);
  k_rankdec<<<8, 256, 0, stream>>>(cla, reg, anchors, hp, wp, cand_keys, cand_box,
                                   cand_area, cand_score, cand_cls, cand_valid);
  k_supres<<<16, 1024, 0, stream>>>(cand_box, cand_area, cand_valid, cand_score,
                                    cand_cls, sup, meta, out);
}

// Round 4
// 313.902 us; speedup vs baseline: 1.2073x; 1.0489x over previous
//
#include <hip/hip_runtime.h>
#include <stdint.h>

// ---------------------------------------------------------------------------
// EfficientDet post-process, multi-dispatch (grid.sync() proved ~100us/sync on
// 8-XCD gfx950 -> kernel-boundary sync instead). 5 nodes:
//   memset(hist0 16KB) ->
//   k_score   : zero 4.2MB aux region + per-anchor max over 80 cls + 12b hist0
//   k_hist1   : scan(hist0)->d0; 2^20-bin leaf hist + 4096-group summary
//   k_gather  : scans(hist0,summary,leaf group) -> exact 32b threshold T,
//               per-block-aggregated gather (exactly top-1000 (+exact ties))
//   k_supdec  : fused decode + key-order IoU bitmatrix + last-block-ticket
//               parallel-fixpoint NMS + rank-for-output + argmax + write
// Round-3 lesson: fixpoint resolve works (329us, all kernels <81us); per-node
// overhead dominates -> k_rankdec eliminated. Greedy order is encoded in the
// 64-bit ck=(key,~idx): suppressor = (ck_j > ck_i) && IoU>0.5 on UNSORTED
// slots; rank computed once in last block only for output placement.
// ---------------------------------------------------------------------------

#define NK 1000
#define CAP 2048
#define NS 1024  // NMS slot count (>= 1000 + exact-float-tie margin)
#define NCLS 80
#define NW 16
typedef unsigned long long ull;

static inline __device__ unsigned fkey(float f) {
  unsigned u = __float_as_uint(f);
  return (u & 0x80000000u) ? ~u : (u | 0x80000000u);
}
static inline __device__ float fkey_inv(unsigned k) {
  unsigned u = (k & 0x80000000u) ? (k & 0x7fffffffu) : ~k;
  return __uint_as_float(u);
}

// Redundant per-block selection scan (blockDim.x >= 256 required; first 256
// threads participate). Finds largest digit with suffix-count >= k and the
// count strictly above that digit.
__device__ __forceinline__ void scan_select(const unsigned* __restrict__ gh, int nbins,
                                            unsigned k, unsigned* s_sum, unsigned* s_res,
                                            unsigned& digit, unsigned& cum_above) {
  int t = threadIdx.x;
  int chunk = nbins >> 8;
  if (chunk < 1) chunk = 1;
  int base = t * chunk;
  unsigned s = 0;
  if (t < 256)
    for (int b = 0; b < chunk; ++b) s += gh[base + b];
  if (t < 256) s_sum[t] = s;
  __syncthreads();
  if (t < 256) {
    unsigned ca = 0;
    for (int u = t + 1; u < 256; ++u) ca += s_sum[u];
    if (ca < k && ca + s >= k) {  // exactly one thread
      unsigned cum = ca;
      for (int b = chunk - 1; b >= 0; --b) {
        unsigned c = gh[base + b];
        if (cum + c >= k) { s_res[0] = (unsigned)(base + b); s_res[1] = cum; break; }
        cum += c;
      }
    }
  }
  __syncthreads();
  digit = s_res[0];
  cum_above = s_res[1];
  __syncthreads();
}

// ---- K1: zero aux region + score + key + top-12-bit histogram --------------
__global__ __launch_bounds__(256) void k_score(const float* __restrict__ cla,
                                               unsigned* __restrict__ keys,
                                               unsigned* __restrict__ hist0,
                                               uint4* __restrict__ zreg, int nz4,
                                               int A) {
  __shared__ unsigned lh[4096];
  int t = threadIdx.x;
  // Zero leaf hist (4MB) + summary + meta + cand_keys (consumed only by later
  // dispatches, so no intra-kernel ordering needed). Replaces a memset node.
  {
    const uint4 z = make_uint4(0u, 0u, 0u, 0u);
    int stride = gridDim.x * 256;
    for (int i = blockIdx.x * 256 + t; i < nz4; i += stride) zreg[i] = z;
  }
  for (int i = t; i < 4096; i += 256) lh[i] = 0u;
  __syncthreads();
  const int lane = t & 63, wib = t >> 6;
  const int gwave = blockIdx.x * 4 + wib, nwaves = gridDim.x * 4;
  const int q = lane >> 2, sub = lane & 3;  // 4 lanes per 320B anchor row
  const int ntask = (A + 15) >> 4;
  for (int task = gwave; task < ntask; task += nwaves) {
    int a = task * 16 + q;
    float m = -3.402823466e38f;
    if (a < A) {
      const float4* p = (const float4*)(cla + (size_t)a * NCLS);
#pragma unroll
      for (int j = 0; j < 5; ++j) {
        float4 v = p[sub + j * 4];
        m = fmaxf(m, fmaxf(fmaxf(v.x, v.y), fmaxf(v.z, v.w)));
      }
    }
    m = fmaxf(m, __shfl_xor(m, 1, 64));
    m = fmaxf(m, __shfl_xor(m, 2, 64));
    if (sub == 0 && a < A) {
      unsigned key = fkey(m);
      keys[a] = key;
      atomicAdd(&lh[key >> 20], 1u);
    }
  }
  __syncthreads();
  for (int i = t; i < 4096; i += 256) {
    unsigned c = lh[i];
    if (c) atomicAdd(&hist0[i], c);
  }
}

// ---- K2: 2^20-bin leaf histogram + 4096-group summary ----------------------
__global__ __launch_bounds__(256) void k_hist1(const unsigned* __restrict__ keys,
                                               const unsigned* __restrict__ hist0,
                                               unsigned* __restrict__ leaf,
                                               unsigned* __restrict__ summary, int A) {
  __shared__ unsigned lh[4096];
  __shared__ unsigned s_sum[256];
  __shared__ unsigned s_res[2];
  int t = threadIdx.x;
  unsigned d0, ca;
  scan_select(hist0, 4096, NK, s_sum, s_res, d0, ca);
  for (int i = t; i < 4096; i += 256) lh[i] = 0u;
  __syncthreads();
  int tid = blockIdx.x * 256 + t, nthr = gridDim.x * 256;
  for (int a = tid; a < A; a += nthr) {
    unsigned key = keys[a];
    if ((key >> 20) == d0) {
      unsigned low = key & 0xFFFFFu;
      atomicAdd(&leaf[low], 1u);       // scattered over 1M bins -> low contention
      atomicAdd(&lh[low >> 8], 1u);    // LDS-aggregated group summary
    }
  }
  __syncthreads();
  for (int i = t; i < 4096; i += 256) {
    unsigned c = lh[i];
    if (c) atomicAdd(&summary[i], c);
  }
}

// ---- K3: exact 32-bit threshold + gather (per-block LDS aggregation) -------
__global__ __launch_bounds__(256) void k_gather(const unsigned* __restrict__ keys,
                                                const unsigned* __restrict__ hist0,
                                                const unsigned* __restrict__ leaf,
                                                const unsigned* __restrict__ summary,
                                                unsigned* __restrict__ meta,
                                                ull* __restrict__ cand_keys, int A) {
  __shared__ unsigned s_sum[256];
  __shared__ unsigned s_res[2];
  __shared__ ull lbuf[1024];
  __shared__ unsigned lcnt;
  __shared__ unsigned gbase;
  int t = threadIdx.x;
  unsigned k_rem = NK, d0, g, b, ca;
  scan_select(hist0, 4096, k_rem, s_sum, s_res, d0, ca);
  k_rem -= ca;
  scan_select(summary, 4096, k_rem, s_sum, s_res, g, ca);
  k_rem -= ca;
  scan_select(leaf + (size_t)g * 256, 256, k_rem, s_sum, s_res, b, ca);
  // identical bit layout to the old 3-level threshold: d0(12)|mid(12)|low(8)
  const unsigned T = (d0 << 20) | (g << 8) | b;  // 1000th-largest key (exact)
  if (t == 0) lcnt = 0u;
  __syncthreads();
  int tid = blockIdx.x * 256 + t, nthr = gridDim.x * 256;
  for (int a = tid; a < A; a += nthr) {
    unsigned key = keys[a];
    if (key >= T) {
      unsigned pos = atomicAdd(&lcnt, 1u);
      if (pos < 1024)
        lbuf[pos] = ((ull)key << 32) | (ull)(~(unsigned)a);  // (score desc, idx asc)
    }
  }
  __syncthreads();
  if (t == 0) gbase = (lcnt > 0) ? atomicAdd(&meta[0], lcnt) : 0u;
  __syncthreads();
  unsigned n = lcnt < 1024u ? lcnt : 1024u;
  for (unsigned i = t; i < n; i += 256) {
    unsigned pos = gbase + i;
    if (pos < CAP) cand_keys[pos] = lbuf[i];
  }
}

// ---- K4: decode + key-order IoU bitmatrix + ticket + fixpoint + output -----
// Slots are UNSORTED candidates (exactly top-1000 + exact-score ties, rest
// zero-key padding). Greedy order is the 64-bit ck descending order.
__global__ __launch_bounds__(1024) void k_supdec(
    const float* __restrict__ cla, const float* __restrict__ reg,
    const float* __restrict__ anchors, const int* __restrict__ hp,
    const int* __restrict__ wp, const ull* __restrict__ cand_keys,
    ull* __restrict__ sup, unsigned* __restrict__ meta,
    float* __restrict__ out) {
  __shared__ ull ckl[NS];
  __shared__ float4 bx[NS];
  __shared__ float ar[NS];
  __shared__ unsigned keptm[32], notm[32];  // NS-bit kept / decided-not masks
  __shared__ int s_chg;
  __shared__ int s_last;
  int t = threadIdx.x;
  ckl[t] = cand_keys[t];
  __syncthreads();
  // ---- redundant per-block decode: 1 slot per thread (trivial)
  ull ck = ckl[t];
  float score = 0.0f;
  bool valid = false;
  if (ck != 0ull) {
    unsigned a = ~(unsigned)(ck & 0xFFFFFFFFull);
    score = fkey_inv((unsigned)(ck >> 32));
    float W1 = (float)wp[0] - 1.0f;
    float H1 = (float)hp[0] - 1.0f;
    float4 dd = ((const float4*)reg)[a];
    float4 an = ((const float4*)anchors)[a];
    float wa = an.z - an.x, ha = an.w - an.y;
    float cxa = an.x + 0.5f * wa, cya = an.y + 0.5f * ha;
    float cx = cxa + dd.x * wa, cy = cya + dd.y * ha;
    float w = wa * expf(dd.z), h = ha * expf(dd.w);
    float x1 = fminf(fmaxf(cx - 0.5f * w, 0.0f), W1);
    float y1 = fminf(fmaxf(cy - 0.5f * h, 0.0f), H1);
    float x2 = fminf(fmaxf(cx + 0.5f * w, 0.0f), W1);
    float y2 = fminf(fmaxf(cy + 0.5f * h, 0.0f), H1);
    bx[t] = make_float4(x1, y1, x2, y2);
    ar[t] = fmaxf(x2 - x1, 0.0f) * fmaxf(y2 - y1, 0.0f);
    valid = (score > 0.5f);
  } else {
    bx[t] = make_float4(0.f, 0.f, 0.f, 0.f);
    ar[t] = 0.0f;
  }
  __syncthreads();
  // ---- IoU + key-order suppression word: 16 blocks x 1024 thr = NS*NW pairs.
  // j staggered by w -> distinct bank groups across the 16 w-lanes (2-way,
  // free) instead of 16-way conflict.
  {
    int gidx = blockIdx.x * 1024 + t;
    int i = gidx >> 4, w = gidx & 15;
    ull cki = ckl[i];
    float4 bi = bx[i];
    float ai = ar[i];
    ull bits = 0ull;
    int j0 = w * 64;
#pragma unroll 4
    for (int s = 0; s < 64; ++s) {
      int jj = (s + w) & 63;
      int j = j0 + jj;
      ull ckj = ckl[j];
      if (ckj > cki) {  // j precedes i in greedy order
        float4 bj = bx[j];
        float xx1 = fmaxf(bi.x, bj.x), yy1 = fmaxf(bi.y, bj.y);
        float xx2 = fminf(bi.z, bj.z), yy2 = fminf(bi.w, bj.w);
        float inter = fmaxf(xx2 - xx1, 0.0f) * fmaxf(yy2 - yy1, 0.0f);
        float uni = ai + ar[j] - inter;
        float iou = inter / fmaxf(uni, 1e-8f);
        if (iou > 0.5f) bits |= (1ull << jj);
      }
    }
    sup[(size_t)i * NW + w] = bits;
  }
  // ---- release our sup rows, take a ticket (agent scope: per-XCD L2s are
  // not cross-coherent; consumer reads sup via agent-scope atomic loads).
  __threadfence();
  __syncthreads();
  if (t == 0) {
    unsigned done = __hip_atomic_fetch_add(&meta[1], 1u, __ATOMIC_ACQ_REL,
                                           __HIP_MEMORY_SCOPE_AGENT);
    s_last = (done == gridDim.x - 1) ? 1 : 0;
    s_chg = 0;
  }
  __syncthreads();
  if (!s_last) return;
  // ---- last block: rank (output placement + top-NK gate). LDS broadcast
  // reads: every lane scans ckl[0..NS) in the same order -> conflict-free.
  unsigned rnk = 0;
  for (int j = 0; j < NS; ++j) rnk += (ckl[j] > ck) ? 1u : 0u;
  if (t < 32) { keptm[t] = 0u; notm[t] = 0u; }
  bool active = (ck != 0ull) && (rnk < NK);
  bool decided = (!active) || (!valid);
  ull rw[NW];  // fully unrolled static indexing only -> registers, not scratch
#pragma unroll
  for (int w = 0; w < NW; ++w)
    rw[w] = __hip_atomic_load(&sup[(size_t)t * NW + w], __ATOMIC_RELAXED,
                              __HIP_MEMORY_SCOPE_AGENT);
  __syncthreads();
  // pad slots, rank>=NK ties, and invalid-score rows are force-dropped here,
  // so they can never suppress (not in keptm) and never stall pot (in notm).
  if (decided) atomicOr(&notm[t >> 5], 1u << (t & 31));
  __syncthreads();
  // ---- monotone-fixpoint greedy NMS (order = ck desc; relation pre-masked
  // by ckj>cki in the bitmatrix, so no triangle masking needed here).
  for (int round = 0; round < NS; ++round) {
    if (!decided) {
      ull hit = 0ull, pot = 0ull;
#pragma unroll
      for (int w = 0; w < NW; ++w) {
        ull km = ((ull)keptm[2 * w + 1] << 32) | (ull)keptm[2 * w];
        ull nm = ((ull)notm[2 * w + 1] << 32) | (ull)notm[2 * w];
        hit |= rw[w] & km;
        pot |= rw[w] & ~(km | nm);
      }
      if (hit) {
        decided = true;
        atomicOr(&notm[t >> 5], 1u << (t & 31));
        s_chg = 1;  // benign race: all writers store 1
      } else if (!pot) {
        decided = true;
        atomicOr(&keptm[t >> 5], 1u << (t & 31));
        s_chg = 1;
      }
    }
    __syncthreads();
    if (s_chg == 0) break;
    __syncthreads();
    if (t == 0) s_chg = 0;
    __syncthreads();
  }
  // ---- argmax class (kept rows only) + output write at rank position
  if (active) {
    bool kp = (keptm[t >> 5] >> (t & 31)) & 1u;
    int ci = 0;
    if (kp) {
      unsigned a = ~(unsigned)(ck & 0xFFFFFFFFull);
      const float* row = cla + (size_t)a * NCLS;
      float m = -3.402823466e38f;
#pragma unroll
      for (int j = 0; j < NCLS; ++j) {
        float v = row[j];
        if (v > m) { m = v; ci = j; }
      }
    }
    out[rnk] = kp ? score : 0.0f;
    out[NK + rnk] = kp ? (float)ci : -1.0f;  // int output read as float
    float4 bo = bx[t];
    ((float4*)(out + 2 * NK))[rnk] = kp ? bo : make_float4(0.f, 0.f, 0.f, 0.f);
  }
}

extern "C" void kernel_launch(void* const* d_in, const int* in_sizes, int n_in,
                              void* d_out, int out_size, void* d_ws, size_t ws_size,
                              hipStream_t stream) {
  const float* cla = (const float*)d_in[0];
  const float* reg = (const float*)d_in[1];
  const float* anchors = (const float*)d_in[2];
  const int* hp = (const int*)d_in[3];
  const int* wp = (const int*)d_in[4];
  float* out = (float*)d_out;
  int A = in_sizes[2] / 4;  // 441936

  char* ws = (char*)d_ws;
  size_t off = 0;
  auto carve = [&](size_t bytes) -> void* {
    void* p = ws + off;
    off += bytes;
    off = (off + 255) & ~(size_t)255;
    return p;
  };
  unsigned* keys = (unsigned*)carve((size_t)A * 4);
  unsigned* hist0 = (unsigned*)carve(4096 * 4);  // zeroed by the memset node
  // contiguous region zeroed inside k_score: leaf|summary|meta|cand_keys
  char* zbase = ws + off;
  unsigned* leaf = (unsigned*)carve((size_t)(1 << 20) * 4);  // 4 MB
  unsigned* summary = (unsigned*)carve(4096 * 4);
  unsigned* meta = (unsigned*)carve(2 * 4);  // [0]=cand_count [1]=ticket
  ull* cand_keys = (ull*)carve(CAP * 8);
  size_t zbytes = (size_t)((ws + off) - zbase);
  int nz4 = (int)(zbytes / 16);
  ull* sup = (ull*)carve((size_t)NS * NW * 8);
  (void)ws_size;
  (void)n_in;
  (void)out_size;

  hipMemsetAsync(hist0, 0, 4096 * 4, stream);
  k_score<<<1024, 256, 0, stream>>>(cla, keys, hist0, (uint4*)zbase, nz4, A);
  k_hist1<<<512, 256, 0, stream>>>(keys, hist0, leaf, summary, A);
  k_gather<<<512, 256, 0, stream>>>(keys, hist0, leaf, summary, meta, cand_keys, A);
  k_supdec<<<16, 1024, 0, stream>>>(cla, reg, anchors, hp, wp, cand_keys, sup, meta,
                                    out);
}